// Round 1
// baseline (514.766 us; speedup 1.0000x reference)
//
#include <hip/hip_runtime.h>

typedef unsigned short u16;
typedef __attribute__((ext_vector_type(8))) short short8;
typedef __attribute__((ext_vector_type(8))) unsigned short u16x8;
typedef __attribute__((ext_vector_type(4))) unsigned short u16x4;
typedef __attribute__((ext_vector_type(4))) float f32x4;

#define N_TOKENS 32768
#define EMBED 512
#define NCLS 16
#define NBATCH 8
#define NHEAD 8
#define DHEAD 64

__device__ __forceinline__ u16 f2bf(float f) {
  unsigned u = __float_as_uint(f);
  u += 0x7fffu + ((u >> 16) & 1u);   // RNE
  return (u16)(u >> 16);
}
__device__ __forceinline__ float bf2f(u16 b) {
  return __uint_as_float(((unsigned)b) << 16);
}

__device__ __forceinline__ void async16(const u16* g, u16* l) {
  __builtin_amdgcn_global_load_lds(
      (__attribute__((address_space(1))) const unsigned int*)(const void*)g,
      (__attribute__((address_space(3))) unsigned int*)(void*)l,
      16, 0, 0);
}

// ---------------- fp32 -> bf16 converter (4 elems/thread) ----------------
__global__ __launch_bounds__(256) void cvt_bf16(const float4* __restrict__ in,
                                                u16x4* __restrict__ out, int n4) {
  int i = blockIdx.x * blockDim.x + threadIdx.x;
  if (i >= n4) return;
  float4 v = in[i];
  u16x4 o;
  o[0] = f2bf(v.x); o[1] = f2bf(v.y); o[2] = f2bf(v.z); o[3] = f2bf(v.w);
  out[i] = o;
}

// ---------------- K/V projection into attention-friendly layouts ----------------
// kproj[b][h][d][l] = sum_e key[l][b][e]*Wk[h*64+d][e] + bk
// vproj[b][h][l][d] = sum_e val[l][b][e]*Wv[h*64+d][e] + bv
__global__ __launch_bounds__(256) void kvproj_kernel(
    const float* __restrict__ key, const float* __restrict__ val,
    const float* __restrict__ Wk, const float* __restrict__ bk,
    const float* __restrict__ Wv, const float* __restrict__ bv,
    float* __restrict__ kproj, float* __restrict__ vproj) {
  int t = blockIdx.x * blockDim.x + threadIdx.x;   // [0, 2*65536)
  const bool isV = t >= 65536;                      // wave-uniform (65536 % 64 == 0)
  int idx = t & 65535;
  int f = idx & 511;
  int bl = idx >> 9;
  int l = bl & 15;
  int b = bl >> 4;
  const float* src = isV ? val : key;
  const float* W = isV ? Wv : Wk;
  const float* bias = isV ? bv : bk;
  const float4* s4 = (const float4*)(src + (size_t)l * (NBATCH * EMBED) + (size_t)b * EMBED);
  const float4* w4 = (const float4*)(W + (size_t)f * EMBED);
  float acc = 0.f;
#pragma unroll 8
  for (int e = 0; e < EMBED / 4; e++) {
    float4 a = s4[e], w = w4[e];
    acc += a.x * w.x + a.y * w.y + a.z * w.z + a.w * w.w;
  }
  acc += bias[f];
  if (!isV) {
    kproj[((size_t)(b * EMBED + f)) * NCLS + l] = acc;           // [b][h][d][l]
  } else {
    int h = f >> 6, d = f & 63;
    vproj[(size_t)b * (NHEAD * NCLS * DHEAD) + (size_t)h * (NCLS * DHEAD) + l * DHEAD + d] = acc;
  }
}

// ---------------- bf16 GEMM: C[M,N] = A[M,K] * B[N,K]^T + bias ----------------
// m97 structure: 128x128 tile, BK=32, 4 waves (2x2), each wave 4x4 of 16x16 MFMA tiles.
template <int STORE_BF16>
__global__ __launch_bounds__(256) void gemm_bt_128(
    const u16* __restrict__ A, const u16* __restrict__ B,
    const float* __restrict__ bias, void* __restrict__ Cout,
    int M, int N, int K) {
  __shared__ u16 As[128 * 32];
  __shared__ u16 Bs[128 * 32];
  const int tid = threadIdx.x;
  const int lane = tid & 63;
  const int wave = tid >> 6;
  const int wr = (wave >> 1) * 64;
  const int wc = (wave & 1) * 64;
  const int quad = lane >> 4;
  const int l16 = lane & 15;
  const int m0 = blockIdx.y * 128;
  const int n0 = blockIdx.x * 128;

  f32x4 acc[4][4];
  const f32x4 zero = {0.f, 0.f, 0.f, 0.f};
#pragma unroll
  for (int i = 0; i < 4; i++)
#pragma unroll
    for (int j = 0; j < 4; j++) acc[i][j] = zero;

  const int c0 = tid;
  const int c1 = tid + 256;
  const size_t aoff0 = (size_t)(m0 + (c0 >> 2)) * K + (c0 & 3) * 8;
  const size_t aoff1 = (size_t)(m0 + (c1 >> 2)) * K + (c1 & 3) * 8;
  const size_t boff0 = (size_t)(n0 + (c0 >> 2)) * K + (c0 & 3) * 8;
  const size_t boff1 = (size_t)(n0 + (c1 >> 2)) * K + (c1 & 3) * 8;

  for (int k0 = 0; k0 < K; k0 += 32) {
    __syncthreads();
    async16(A + aoff0 + k0, &As[c0 * 8]);
    async16(A + aoff1 + k0, &As[c1 * 8]);
    async16(B + boff0 + k0, &Bs[c0 * 8]);
    async16(B + boff1 + k0, &Bs[c1 * 8]);
    __syncthreads();

    short8 af[4], bf[4];
#pragma unroll
    for (int mi = 0; mi < 4; mi++)
      af[mi] = *(const short8*)&As[(wr + mi * 16 + l16) * 32 + quad * 8];
#pragma unroll
    for (int ni = 0; ni < 4; ni++)
      bf[ni] = *(const short8*)&Bs[(wc + ni * 16 + l16) * 32 + quad * 8];
#pragma unroll
    for (int mi = 0; mi < 4; mi++)
#pragma unroll
      for (int ni = 0; ni < 4; ni++)
        acc[mi][ni] = __builtin_amdgcn_mfma_f32_16x16x32_bf16(af[mi], bf[ni], acc[mi][ni], 0, 0, 0);
  }

#pragma unroll
  for (int mi = 0; mi < 4; mi++) {
#pragma unroll
    for (int ni = 0; ni < 4; ni++) {
      const int col = n0 + wc + ni * 16 + l16;
      const float bv = bias[col];
#pragma unroll
      for (int r = 0; r < 4; r++) {
        const int row = m0 + wr + mi * 16 + quad * 4 + r;
        const float v = acc[mi][ni][r] + bv;
        if (STORE_BF16)
          ((u16*)Cout)[(size_t)row * N + col] = f2bf(v);
        else
          ((float*)Cout)[(size_t)row * N + col] = v;
      }
    }
  }
}

// ---------------- attention core: one thread per token ----------------
__global__ __launch_bounds__(256) void attn_kernel(
    const u16* __restrict__ q,        // [N_TOKENS, EMBED] bf16
    const float* __restrict__ kproj,  // [B,H,D,L] fp32
    const float* __restrict__ vproj,  // [B,H,L,D] fp32
    const int* __restrict__ bidx,
    u16* __restrict__ ctx) {          // [N_TOKENS, EMBED] bf16
  const int n = blockIdx.x * blockDim.x + threadIdx.x;
  const int b = bidx[n];
  for (int h = 0; h < NHEAD; h++) {
    const u16* qrow = q + (size_t)n * EMBED + h * DHEAD;
    float qh[64];
#pragma unroll
    for (int i = 0; i < 8; i++) {
      u16x8 u = *(const u16x8*)(qrow + i * 8);
#pragma unroll
      for (int j = 0; j < 8; j++) qh[i * 8 + j] = bf2f(u[j]) * 0.125f;  // scale = D^-0.5
    }
    const float* kb = kproj + (size_t)(b * NHEAD + h) * (DHEAD * NCLS);
    float s[16];
#pragma unroll
    for (int l = 0; l < 16; l++) s[l] = 0.f;
#pragma unroll
    for (int d = 0; d < 64; d++) {
      const float qd = qh[d];
      const float4* k4 = (const float4*)(kb + d * 16);
#pragma unroll
      for (int l4 = 0; l4 < 4; l4++) {
        float4 kk = k4[l4];
        s[l4 * 4 + 0] += qd * kk.x;
        s[l4 * 4 + 1] += qd * kk.y;
        s[l4 * 4 + 2] += qd * kk.z;
        s[l4 * 4 + 3] += qd * kk.w;
      }
    }
    float mx = s[0];
#pragma unroll
    for (int l = 1; l < 16; l++) mx = fmaxf(mx, s[l]);
    float p[16];
    float sum = 0.f;
#pragma unroll
    for (int l = 0; l < 16; l++) {
      p[l] = __expf(s[l] - mx);
      sum += p[l];
    }
    const float inv = 1.f / sum;
    float c[64];
#pragma unroll
    for (int d = 0; d < 64; d++) c[d] = 0.f;
    const float* vb = vproj + (size_t)(b * NHEAD + h) * (NCLS * DHEAD);
#pragma unroll
    for (int l = 0; l < 16; l++) {
      const float pl = p[l] * inv;
      const float4* v4 = (const float4*)(vb + l * DHEAD);
#pragma unroll
      for (int d4 = 0; d4 < 16; d4++) {
        float4 vv = v4[d4];
        c[d4 * 4 + 0] += pl * vv.x;
        c[d4 * 4 + 1] += pl * vv.y;
        c[d4 * 4 + 2] += pl * vv.z;
        c[d4 * 4 + 3] += pl * vv.w;
      }
    }
    u16* orow = ctx + (size_t)n * EMBED + h * DHEAD;
#pragma unroll
    for (int i = 0; i < 8; i++) {
      u16x8 u;
#pragma unroll
      for (int j = 0; j < 8; j++) u[j] = f2bf(c[i * 8 + j]);
      *(u16x8*)(orow + i * 8) = u;
    }
  }
}

extern "C" void kernel_launch(void* const* d_in, const int* in_sizes, int n_in,
                              void* d_out, int out_size, void* d_ws, size_t ws_size,
                              hipStream_t stream) {
  const float* query = (const float*)d_in[0];
  const float* keyt = (const float*)d_in[1];
  const float* valt = (const float*)d_in[2];
  const int* bidx = (const int*)d_in[3];
  // d_in[4] = batch_size (scalar, fixed = 8)
  const float* Wq = (const float*)d_in[5];
  const float* bq = (const float*)d_in[6];
  const float* Wk = (const float*)d_in[7];
  const float* bk = (const float*)d_in[8];
  const float* Wv = (const float*)d_in[9];
  const float* bv = (const float*)d_in[10];
  const float* Wo = (const float*)d_in[11];
  const float* bo = (const float*)d_in[12];
  float* out = (float*)d_out;

  // workspace layout (bytes)
  unsigned char* w = (unsigned char*)d_ws;
  u16* qbf = (u16*)(w);                      //  33,554,432: query bf16 [N,E]
  u16* qout = (u16*)(w + 33554432ull);       //  33,554,432: Q bf16 [N,E]
  u16* ctxb = (u16*)(w + 67108864ull);       //  33,554,432: ctx bf16 [N,E]
  u16* wqb = (u16*)(w + 100663296ull);       //     524,288: Wq bf16
  u16* wob = (u16*)(w + 101187584ull);       //     524,288: Wo bf16
  float* kproj = (float*)(w + 101711872ull); //     262,144: [B,H,D,L]
  float* vproj = kproj + 65536;              //     262,144: [B,H,L,D]

  // 1) converts
  cvt_bf16<<<(N_TOKENS * EMBED / 4 + 255) / 256, 256, 0, stream>>>(
      (const float4*)query, (u16x4*)qbf, N_TOKENS * EMBED / 4);
  cvt_bf16<<<(EMBED * EMBED / 4 + 255) / 256, 256, 0, stream>>>(
      (const float4*)Wq, (u16x4*)wqb, EMBED * EMBED / 4);
  cvt_bf16<<<(EMBED * EMBED / 4 + 255) / 256, 256, 0, stream>>>(
      (const float4*)Wo, (u16x4*)wob, EMBED * EMBED / 4);

  // 2) K/V projections
  kvproj_kernel<<<512, 256, 0, stream>>>(keyt, valt, Wk, bk, Wv, bv, kproj, vproj);

  // 3) Q = query @ Wq^T + bq  (bf16 out)
  gemm_bt_128<1><<<dim3(EMBED / 128, N_TOKENS / 128), 256, 0, stream>>>(
      qbf, wqb, bq, qout, N_TOKENS, EMBED, EMBED);

  // 4) attention core (ctx bf16)
  attn_kernel<<<N_TOKENS / 256, 256, 0, stream>>>(qout, kproj, vproj, bidx, ctxb);

  // 5) out = ctx @ Wo^T + bo (fp32 out)
  gemm_bt_128<0><<<dim3(EMBED / 128, N_TOKENS / 128), 256, 0, stream>>>(
      ctxb, wob, bo, out, N_TOKENS, EMBED, EMBED);
}

// Round 2
// 488.990 us; speedup vs baseline: 1.0527x; 1.0527x over previous
//
#include <hip/hip_runtime.h>

typedef unsigned short u16;
typedef __attribute__((ext_vector_type(8))) short short8;
typedef __attribute__((ext_vector_type(8))) unsigned short u16x8;
typedef __attribute__((ext_vector_type(4))) unsigned short u16x4;
typedef __attribute__((ext_vector_type(4))) float f32x4;

#define N_TOKENS 32768
#define EMBED 512
#define NCLS 16
#define NBATCH 8
#define NHEAD 8
#define DHEAD 64

__device__ __forceinline__ u16 f2bf(float f) {
  unsigned u = __float_as_uint(f);
  u += 0x7fffu + ((u >> 16) & 1u);   // RNE
  return (u16)(u >> 16);
}
__device__ __forceinline__ float bf2f(u16 b) {
  return __uint_as_float(((unsigned)b) << 16);
}

__device__ __forceinline__ void async16(const u16* g, u16* l) {
  __builtin_amdgcn_global_load_lds(
      (__attribute__((address_space(1))) const unsigned int*)(const void*)g,
      (__attribute__((address_space(3))) unsigned int*)(void*)l,
      16, 0, 0);
}

// ---------------- fp32 -> bf16 converter (4 elems/thread) ----------------
__global__ __launch_bounds__(256) void cvt_bf16(const float4* __restrict__ in,
                                                u16x4* __restrict__ out, int n4) {
  int i = blockIdx.x * blockDim.x + threadIdx.x;
  if (i >= n4) return;
  float4 v = in[i];
  u16x4 o;
  o[0] = f2bf(v.x); o[1] = f2bf(v.y); o[2] = f2bf(v.z); o[3] = f2bf(v.w);
  out[i] = o;
}

// ---------------- K/V projection into attention-friendly layouts ----------------
// kproj[b][h][d][l] = sum_e key[l][b][e]*Wk[h*64+d][e] + bk
// vproj[b][h][l][d] = sum_e val[l][b][e]*Wv[h*64+d][e] + bv
__global__ __launch_bounds__(256) void kvproj_kernel(
    const float* __restrict__ key, const float* __restrict__ val,
    const float* __restrict__ Wk, const float* __restrict__ bk,
    const float* __restrict__ Wv, const float* __restrict__ bv,
    float* __restrict__ kproj, float* __restrict__ vproj) {
  int t = blockIdx.x * blockDim.x + threadIdx.x;   // [0, 2*65536)
  const bool isV = t >= 65536;                      // wave-uniform (65536 % 64 == 0)
  int idx = t & 65535;
  int f = idx & 511;
  int bl = idx >> 9;
  int l = bl & 15;
  int b = bl >> 4;
  const float* src = isV ? val : key;
  const float* W = isV ? Wv : Wk;
  const float* bias = isV ? bv : bk;
  const float4* s4 = (const float4*)(src + (size_t)l * (NBATCH * EMBED) + (size_t)b * EMBED);
  const float4* w4 = (const float4*)(W + (size_t)f * EMBED);
  float acc = 0.f;
#pragma unroll 8
  for (int e = 0; e < EMBED / 4; e++) {
    float4 a = s4[e], w = w4[e];
    acc += a.x * w.x + a.y * w.y + a.z * w.z + a.w * w.w;
  }
  acc += bias[f];
  if (!isV) {
    kproj[((size_t)(b * EMBED + f)) * NCLS + l] = acc;           // [b][h][d][l]
  } else {
    int h = f >> 6, d = f & 63;
    vproj[(size_t)b * (NHEAD * NCLS * DHEAD) + (size_t)h * (NCLS * DHEAD) + l * DHEAD + d] = acc;
  }
}

// ---------------- bf16 GEMM: C[M,N] = A[M,K] * B[N,K]^T + bias ----------------
// m97 structure: 128x128 tile, BK=32, 4 waves (2x2), each wave 4x4 of 16x16 MFMA tiles.
template <int STORE_BF16>
__global__ __launch_bounds__(256) void gemm_bt_128(
    const u16* __restrict__ A, const u16* __restrict__ B,
    const float* __restrict__ bias, void* __restrict__ Cout,
    int M, int N, int K) {
  __shared__ u16 As[128 * 32];
  __shared__ u16 Bs[128 * 32];
  const int tid = threadIdx.x;
  const int lane = tid & 63;
  const int wave = tid >> 6;
  const int wr = (wave >> 1) * 64;
  const int wc = (wave & 1) * 64;
  const int quad = lane >> 4;
  const int l16 = lane & 15;
  const int m0 = blockIdx.y * 128;
  const int n0 = blockIdx.x * 128;

  f32x4 acc[4][4];
  const f32x4 zero = {0.f, 0.f, 0.f, 0.f};
#pragma unroll
  for (int i = 0; i < 4; i++)
#pragma unroll
    for (int j = 0; j < 4; j++) acc[i][j] = zero;

  const int c0 = tid;
  const int c1 = tid + 256;
  const size_t aoff0 = (size_t)(m0 + (c0 >> 2)) * K + (c0 & 3) * 8;
  const size_t aoff1 = (size_t)(m0 + (c1 >> 2)) * K + (c1 & 3) * 8;
  const size_t boff0 = (size_t)(n0 + (c0 >> 2)) * K + (c0 & 3) * 8;
  const size_t boff1 = (size_t)(n0 + (c1 >> 2)) * K + (c1 & 3) * 8;

  for (int k0 = 0; k0 < K; k0 += 32) {
    __syncthreads();
    async16(A + aoff0 + k0, &As[c0 * 8]);
    async16(A + aoff1 + k0, &As[c1 * 8]);
    async16(B + boff0 + k0, &Bs[c0 * 8]);
    async16(B + boff1 + k0, &Bs[c1 * 8]);
    __syncthreads();

    short8 af[4], bf[4];
#pragma unroll
    for (int mi = 0; mi < 4; mi++)
      af[mi] = *(const short8*)&As[(wr + mi * 16 + l16) * 32 + quad * 8];
#pragma unroll
    for (int ni = 0; ni < 4; ni++)
      bf[ni] = *(const short8*)&Bs[(wc + ni * 16 + l16) * 32 + quad * 8];
#pragma unroll
    for (int mi = 0; mi < 4; mi++)
#pragma unroll
      for (int ni = 0; ni < 4; ni++)
        acc[mi][ni] = __builtin_amdgcn_mfma_f32_16x16x32_bf16(af[mi], bf[ni], acc[mi][ni], 0, 0, 0);
  }

#pragma unroll
  for (int mi = 0; mi < 4; mi++) {
#pragma unroll
    for (int ni = 0; ni < 4; ni++) {
      const int col = n0 + wc + ni * 16 + l16;
      const float bv = bias[col];
#pragma unroll
      for (int r = 0; r < 4; r++) {
        const int row = m0 + wr + mi * 16 + quad * 4 + r;
        const float v = acc[mi][ni][r] + bv;
        if (STORE_BF16)
          ((u16*)Cout)[(size_t)row * N + col] = f2bf(v);
        else
          ((float*)Cout)[(size_t)row * N + col] = v;
      }
    }
  }
}

// ---------------- attention core: one thread per (token, head) ----------------
// i = n*8 + h: 8 consecutive lanes cover one token's contiguous q row (coalesced);
// k/v reads are 8-way broadcast within the wave (b uniform for sorted tokens).
__global__ __launch_bounds__(256) void attn_kernel(
    const u16* __restrict__ q,        // [N_TOKENS, EMBED] bf16
    const float* __restrict__ kproj,  // [B,H,D,L] fp32
    const float* __restrict__ vproj,  // [B,H,L,D] fp32
    const int* __restrict__ bidx,
    u16* __restrict__ ctx) {          // [N_TOKENS, EMBED] bf16
  const int i = blockIdx.x * blockDim.x + threadIdx.x;
  const int n = i >> 3;
  const int h = i & 7;
  const int b = bidx[n];

  const u16* qrow = q + (size_t)n * EMBED + h * DHEAD;
  float qh[64];
#pragma unroll
  for (int r = 0; r < 8; r++) {
    u16x8 u = *(const u16x8*)(qrow + r * 8);
#pragma unroll
    for (int j = 0; j < 8; j++) qh[r * 8 + j] = bf2f(u[j]) * 0.125f;  // scale = D^-0.5
  }

  const float* kb = kproj + (size_t)(b * NHEAD + h) * (DHEAD * NCLS);
  float s[16];
#pragma unroll
  for (int l = 0; l < 16; l++) s[l] = 0.f;
#pragma unroll
  for (int d = 0; d < 64; d++) {
    const float qd = qh[d];
    const float4* k4 = (const float4*)(kb + d * 16);
#pragma unroll
    for (int l4 = 0; l4 < 4; l4++) {
      float4 kk = k4[l4];
      s[l4 * 4 + 0] += qd * kk.x;
      s[l4 * 4 + 1] += qd * kk.y;
      s[l4 * 4 + 2] += qd * kk.z;
      s[l4 * 4 + 3] += qd * kk.w;
    }
  }

  float mx = s[0];
#pragma unroll
  for (int l = 1; l < 16; l++) mx = fmaxf(mx, s[l]);
  float p[16];
  float sum = 0.f;
#pragma unroll
  for (int l = 0; l < 16; l++) {
    p[l] = __expf(s[l] - mx);
    sum += p[l];
  }
  const float inv = 1.f / sum;

  float c[64];
#pragma unroll
  for (int d = 0; d < 64; d++) c[d] = 0.f;
  const float* vb = vproj + (size_t)(b * NHEAD + h) * (NCLS * DHEAD);
#pragma unroll
  for (int l = 0; l < 16; l++) {
    const float pl = p[l] * inv;
    const float4* v4 = (const float4*)(vb + l * DHEAD);
#pragma unroll
    for (int d4 = 0; d4 < 16; d4++) {
      float4 vv = v4[d4];
      c[d4 * 4 + 0] += pl * vv.x;
      c[d4 * 4 + 1] += pl * vv.y;
      c[d4 * 4 + 2] += pl * vv.z;
      c[d4 * 4 + 3] += pl * vv.w;
    }
  }

  u16* orow = ctx + (size_t)n * EMBED + h * DHEAD;
#pragma unroll
  for (int r = 0; r < 8; r++) {
    u16x8 u;
#pragma unroll
    for (int j = 0; j < 8; j++) u[j] = f2bf(c[r * 8 + j]);
    *(u16x8*)(orow + r * 8) = u;
  }
}

extern "C" void kernel_launch(void* const* d_in, const int* in_sizes, int n_in,
                              void* d_out, int out_size, void* d_ws, size_t ws_size,
                              hipStream_t stream) {
  const float* query = (const float*)d_in[0];
  const float* keyt = (const float*)d_in[1];
  const float* valt = (const float*)d_in[2];
  const int* bidx = (const int*)d_in[3];
  // d_in[4] = batch_size (scalar, fixed = 8)
  const float* Wq = (const float*)d_in[5];
  const float* bq = (const float*)d_in[6];
  const float* Wk = (const float*)d_in[7];
  const float* bk = (const float*)d_in[8];
  const float* Wv = (const float*)d_in[9];
  const float* bv = (const float*)d_in[10];
  const float* Wo = (const float*)d_in[11];
  const float* bo = (const float*)d_in[12];
  float* out = (float*)d_out;

  // workspace layout (bytes)
  unsigned char* w = (unsigned char*)d_ws;
  u16* qbf = (u16*)(w);                      //  33,554,432: query bf16 [N,E]
  u16* qout = (u16*)(w + 33554432ull);       //  33,554,432: Q bf16 [N,E]
  u16* ctxb = (u16*)(w + 67108864ull);       //  33,554,432: ctx bf16 [N,E]
  u16* wqb = (u16*)(w + 100663296ull);       //     524,288: Wq bf16
  u16* wob = (u16*)(w + 101187584ull);       //     524,288: Wo bf16
  float* kproj = (float*)(w + 101711872ull); //     262,144: [B,H,D,L]
  float* vproj = kproj + 65536;              //     262,144: [B,H,L,D]

  // 1) converts
  cvt_bf16<<<(N_TOKENS * EMBED / 4 + 255) / 256, 256, 0, stream>>>(
      (const float4*)query, (u16x4*)qbf, N_TOKENS * EMBED / 4);
  cvt_bf16<<<(EMBED * EMBED / 4 + 255) / 256, 256, 0, stream>>>(
      (const float4*)Wq, (u16x4*)wqb, EMBED * EMBED / 4);
  cvt_bf16<<<(EMBED * EMBED / 4 + 255) / 256, 256, 0, stream>>>(
      (const float4*)Wo, (u16x4*)wob, EMBED * EMBED / 4);

  // 2) K/V projections
  kvproj_kernel<<<512, 256, 0, stream>>>(keyt, valt, Wk, bk, Wv, bv, kproj, vproj);

  // 3) Q = query @ Wq^T + bq  (bf16 out)
  gemm_bt_128<1><<<dim3(EMBED / 128, N_TOKENS / 128), 256, 0, stream>>>(
      qbf, wqb, bq, qout, N_TOKENS, EMBED, EMBED);

  // 4) attention core (ctx bf16), one thread per (token, head)
  attn_kernel<<<N_TOKENS * NHEAD / 256, 256, 0, stream>>>(qout, kproj, vproj, bidx, ctxb);

  // 5) out = ctx @ Wo^T + bo (fp32 out)
  gemm_bt_128<0><<<dim3(EMBED / 128, N_TOKENS / 128), 256, 0, stream>>>(
      ctxb, wob, bo, out, N_TOKENS, EMBED, EMBED);
}

// Round 3
// 330.544 us; speedup vs baseline: 1.5573x; 1.4794x over previous
//
#include <hip/hip_runtime.h>

typedef unsigned short u16;
typedef __attribute__((ext_vector_type(8))) short short8;
typedef __attribute__((ext_vector_type(8))) unsigned short u16x8;
typedef __attribute__((ext_vector_type(4))) unsigned short u16x4;
typedef __attribute__((ext_vector_type(4))) float f32x4;

#define N_TOKENS 32768
#define EMBED 512
#define NCLS 16
#define NBATCH 8
#define NHEAD 8
#define DHEAD 64

__device__ __forceinline__ u16 f2bf(float f) {
  unsigned u = __float_as_uint(f);
  u += 0x7fffu + ((u >> 16) & 1u);   // RNE
  return (u16)(u >> 16);
}
__device__ __forceinline__ float bf2f(u16 b) {
  return __uint_as_float(((unsigned)b) << 16);
}

__device__ __forceinline__ void async16(const u16* g, u16* l) {
  __builtin_amdgcn_global_load_lds(
      (__attribute__((address_space(1))) const unsigned int*)(const void*)g,
      (__attribute__((address_space(3))) unsigned int*)(void*)l,
      16, 0, 0);
}

// ---------------- fp32 -> bf16 converter (4 elems/thread) ----------------
__global__ __launch_bounds__(256) void cvt_bf16(const float4* __restrict__ in,
                                                u16x4* __restrict__ out, int n4) {
  int i = blockIdx.x * blockDim.x + threadIdx.x;
  if (i >= n4) return;
  float4 v = in[i];
  u16x4 o;
  o[0] = f2bf(v.x); o[1] = f2bf(v.y); o[2] = f2bf(v.z); o[3] = f2bf(v.w);
  out[i] = o;
}

// ---------------- K/V projection into attention-friendly layouts ----------------
// kproj[b][h][d][l] = sum_e key[l][b][e]*Wk[h*64+d][e] + bk
// vproj[b][h][l][d] = sum_e val[l][b][e]*Wv[h*64+d][e] + bv
__global__ __launch_bounds__(256) void kvproj_kernel(
    const float* __restrict__ key, const float* __restrict__ val,
    const float* __restrict__ Wk, const float* __restrict__ bk,
    const float* __restrict__ Wv, const float* __restrict__ bv,
    float* __restrict__ kproj, float* __restrict__ vproj) {
  int t = blockIdx.x * blockDim.x + threadIdx.x;   // [0, 2*65536)
  const bool isV = t >= 65536;                      // wave-uniform (65536 % 64 == 0)
  int idx = t & 65535;
  int f = idx & 511;
  int bl = idx >> 9;
  int l = bl & 15;
  int b = bl >> 4;
  const float* src = isV ? val : key;
  const float* W = isV ? Wv : Wk;
  const float* bias = isV ? bv : bk;
  const float4* s4 = (const float4*)(src + (size_t)l * (NBATCH * EMBED) + (size_t)b * EMBED);
  const float4* w4 = (const float4*)(W + (size_t)f * EMBED);
  float acc = 0.f;
#pragma unroll 8
  for (int e = 0; e < EMBED / 4; e++) {
    float4 a = s4[e], w = w4[e];
    acc += a.x * w.x + a.y * w.y + a.z * w.z + a.w * w.w;
  }
  acc += bias[f];
  if (!isV) {
    kproj[((size_t)(b * EMBED + f)) * NCLS + l] = acc;           // [b][h][d][l]
  } else {
    int h = f >> 6, d = f & 63;
    vproj[(size_t)b * (NHEAD * NCLS * DHEAD) + (size_t)h * (NCLS * DHEAD) + l * DHEAD + d] = acc;
  }
}

// ---------------- bf16 GEMM: C[M,N] = A[M,K] * B[N,K]^T + bias ----------------
// m97 structure: 128x128 tile, BK=32, 4 waves (2x2), each wave 4x4 of 16x16 MFMA tiles.
template <int STORE_BF16>
__global__ __launch_bounds__(256) void gemm_bt_128(
    const u16* __restrict__ A, const u16* __restrict__ B,
    const float* __restrict__ bias, void* __restrict__ Cout,
    int M, int N, int K) {
  __shared__ u16 As[128 * 32];
  __shared__ u16 Bs[128 * 32];
  const int tid = threadIdx.x;
  const int lane = tid & 63;
  const int wave = tid >> 6;
  const int wr = (wave >> 1) * 64;
  const int wc = (wave & 1) * 64;
  const int quad = lane >> 4;
  const int l16 = lane & 15;
  const int m0 = blockIdx.y * 128;
  const int n0 = blockIdx.x * 128;

  f32x4 acc[4][4];
  const f32x4 zero = {0.f, 0.f, 0.f, 0.f};
#pragma unroll
  for (int i = 0; i < 4; i++)
#pragma unroll
    for (int j = 0; j < 4; j++) acc[i][j] = zero;

  const int c0 = tid;
  const int c1 = tid + 256;
  const size_t aoff0 = (size_t)(m0 + (c0 >> 2)) * K + (c0 & 3) * 8;
  const size_t aoff1 = (size_t)(m0 + (c1 >> 2)) * K + (c1 & 3) * 8;
  const size_t boff0 = (size_t)(n0 + (c0 >> 2)) * K + (c0 & 3) * 8;
  const size_t boff1 = (size_t)(n0 + (c1 >> 2)) * K + (c1 & 3) * 8;

  for (int k0 = 0; k0 < K; k0 += 32) {
    __syncthreads();
    async16(A + aoff0 + k0, &As[c0 * 8]);
    async16(A + aoff1 + k0, &As[c1 * 8]);
    async16(B + boff0 + k0, &Bs[c0 * 8]);
    async16(B + boff1 + k0, &Bs[c1 * 8]);
    __syncthreads();

    short8 af[4], bf[4];
#pragma unroll
    for (int mi = 0; mi < 4; mi++)
      af[mi] = *(const short8*)&As[(wr + mi * 16 + l16) * 32 + quad * 8];
#pragma unroll
    for (int ni = 0; ni < 4; ni++)
      bf[ni] = *(const short8*)&Bs[(wc + ni * 16 + l16) * 32 + quad * 8];
#pragma unroll
    for (int mi = 0; mi < 4; mi++)
#pragma unroll
      for (int ni = 0; ni < 4; ni++)
        acc[mi][ni] = __builtin_amdgcn_mfma_f32_16x16x32_bf16(af[mi], bf[ni], acc[mi][ni], 0, 0, 0);
  }

#pragma unroll
  for (int mi = 0; mi < 4; mi++) {
#pragma unroll
    for (int ni = 0; ni < 4; ni++) {
      const int col = n0 + wc + ni * 16 + l16;
      const float bv = bias[col];
#pragma unroll
      for (int r = 0; r < 4; r++) {
        const int row = m0 + wr + mi * 16 + quad * 4 + r;
        const float v = acc[mi][ni][r] + bv;
        if (STORE_BF16)
          ((u16*)Cout)[(size_t)row * N + col] = f2bf(v);
        else
          ((float*)Cout)[(size_t)row * N + col] = v;
      }
    }
  }
}

// ---------------- attention core: one thread per (token, head), LDS-staged k/v ----
// Block = 32 tokens x 8 heads. Tokens are sorted by batch -> b uniform per block
// except at ~7 boundary blocks (those threads read k/v from global, rare).
// LDS layout: per-head stride 1028 words (+4 pad) -> the 8 distinct per-instr
// addresses (one per h) start at banks {0,4,...,28}: b128 reads tile all 32
// banks conflict-free; the 8 token-duplicate lanes broadcast.
#define HSTRIDE 1028
__global__ __launch_bounds__(256) void attn_kernel(
    const u16* __restrict__ q,        // [N_TOKENS, EMBED] bf16
    const float* __restrict__ kproj,  // [B,H,D,L] fp32 (b*8192 + h*1024 + d*16 + l)
    const float* __restrict__ vproj,  // [B,H,L,D] fp32 (b*8192 + h*1024 + l*64 + d)
    const int* __restrict__ bidx,
    u16* __restrict__ ctx) {          // [N_TOKENS, EMBED] bf16
  __shared__ float smem[2 * 8 * HSTRIDE];   // k then v, 65792 B
  const int tid = threadIdx.x;
  const int i = blockIdx.x * 256 + tid;
  const int n = i >> 3;
  const int h = i & 7;
  const int b = bidx[n];
  const int b0 = bidx[blockIdx.x * 32];     // block's dominant batch

  // issue q loads early (independent of staging)
  const u16* qrow = q + (size_t)n * EMBED + h * DHEAD;
  u16x8 qraw[8];
#pragma unroll
  for (int r = 0; r < 8; r++) qraw[r] = *(const u16x8*)(qrow + r * 8);

  // stage k/v for b0: 2048 float4 each? k: 8192 floats = 2048 f4; v same.
  {
    const float4* kg = (const float4*)(kproj + (size_t)b0 * 8192);
    const float4* vg = (const float4*)(vproj + (size_t)b0 * 8192);
#pragma unroll
    for (int it = 0; it < 8; it++) {
      int j = tid + it * 256;                 // f4 index in [0,2048)
      int e = j * 4;
      int hh = e >> 10;
      int rem = e & 1023;
      float4 kk = kg[j];
      float4 vv = vg[j];
      *(float4*)&smem[hh * HSTRIDE + rem] = kk;
      *(float4*)&smem[8 * HSTRIDE + hh * HSTRIDE + rem] = vv;
    }
  }
  __syncthreads();

  float qh[64];
#pragma unroll
  for (int r = 0; r < 8; r++)
#pragma unroll
    for (int j = 0; j < 8; j++) qh[r * 8 + j] = bf2f(qraw[r][j]);

  float s[16];
#pragma unroll
  for (int l = 0; l < 16; l++) s[l] = 0.f;

  if (b == b0) {
    const float* kb = &smem[h * HSTRIDE];
#pragma unroll
    for (int d = 0; d < 64; d++) {
      const float qd = qh[d];
#pragma unroll
      for (int l4 = 0; l4 < 4; l4++) {
        float4 kk = *(const float4*)(kb + d * 16 + l4 * 4);
        s[l4 * 4 + 0] += qd * kk.x;
        s[l4 * 4 + 1] += qd * kk.y;
        s[l4 * 4 + 2] += qd * kk.z;
        s[l4 * 4 + 3] += qd * kk.w;
      }
    }
  } else {
    const float* kb = kproj + (size_t)(b * 8 + h) * 1024;
#pragma unroll
    for (int d = 0; d < 64; d++) {
      const float qd = qh[d];
#pragma unroll
      for (int l4 = 0; l4 < 4; l4++) {
        float4 kk = *(const float4*)(kb + d * 16 + l4 * 4);
        s[l4 * 4 + 0] += qd * kk.x;
        s[l4 * 4 + 1] += qd * kk.y;
        s[l4 * 4 + 2] += qd * kk.z;
        s[l4 * 4 + 3] += qd * kk.w;
      }
    }
  }

  float mx = s[0];
#pragma unroll
  for (int l = 1; l < 16; l++) mx = fmaxf(mx, s[l]);
  float p[16];
  float sum = 0.f;
#pragma unroll
  for (int l = 0; l < 16; l++) {
    p[l] = __expf((s[l] - mx) * 0.125f);      // scale = D^-0.5 folded here
    sum += p[l];
  }
  const float inv = 1.f / sum;

  float c[64];
#pragma unroll
  for (int d = 0; d < 64; d++) c[d] = 0.f;

  if (b == b0) {
    const float* vb = &smem[8 * HSTRIDE + h * HSTRIDE];
#pragma unroll
    for (int l = 0; l < 16; l++) {
      const float pl = p[l] * inv;
#pragma unroll
      for (int d4 = 0; d4 < 16; d4++) {
        float4 vv = *(const float4*)(vb + l * 64 + d4 * 4);
        c[d4 * 4 + 0] += pl * vv.x;
        c[d4 * 4 + 1] += pl * vv.y;
        c[d4 * 4 + 2] += pl * vv.z;
        c[d4 * 4 + 3] += pl * vv.w;
      }
    }
  } else {
    const float* vb = vproj + (size_t)(b * 8 + h) * 1024;
#pragma unroll
    for (int l = 0; l < 16; l++) {
      const float pl = p[l] * inv;
#pragma unroll
      for (int d4 = 0; d4 < 16; d4++) {
        float4 vv = *(const float4*)(vb + l * 64 + d4 * 4);
        c[d4 * 4 + 0] += pl * vv.x;
        c[d4 * 4 + 1] += pl * vv.y;
        c[d4 * 4 + 2] += pl * vv.z;
        c[d4 * 4 + 3] += pl * vv.w;
      }
    }
  }

  u16* orow = ctx + (size_t)n * EMBED + h * DHEAD;
#pragma unroll
  for (int r = 0; r < 8; r++) {
    u16x8 u;
#pragma unroll
    for (int j = 0; j < 8; j++) u[j] = f2bf(c[r * 8 + j]);
    *(u16x8*)(orow + r * 8) = u;
  }
}

extern "C" void kernel_launch(void* const* d_in, const int* in_sizes, int n_in,
                              void* d_out, int out_size, void* d_ws, size_t ws_size,
                              hipStream_t stream) {
  const float* query = (const float*)d_in[0];
  const float* keyt = (const float*)d_in[1];
  const float* valt = (const float*)d_in[2];
  const int* bidx = (const int*)d_in[3];
  // d_in[4] = batch_size (scalar, fixed = 8)
  const float* Wq = (const float*)d_in[5];
  const float* bq = (const float*)d_in[6];
  const float* Wk = (const float*)d_in[7];
  const float* bk = (const float*)d_in[8];
  const float* Wv = (const float*)d_in[9];
  const float* bv = (const float*)d_in[10];
  const float* Wo = (const float*)d_in[11];
  const float* bo = (const float*)d_in[12];
  float* out = (float*)d_out;

  // workspace layout (bytes)
  unsigned char* w = (unsigned char*)d_ws;
  u16* qbf = (u16*)(w);                      //  33,554,432: query bf16 [N,E]
  u16* qout = (u16*)(w + 33554432ull);       //  33,554,432: Q bf16 [N,E]
  u16* ctxb = (u16*)(w + 67108864ull);       //  33,554,432: ctx bf16 [N,E]
  u16* wqb = (u16*)(w + 100663296ull);       //     524,288: Wq bf16
  u16* wob = (u16*)(w + 101187584ull);       //     524,288: Wo bf16
  float* kproj = (float*)(w + 101711872ull); //     262,144: [B,H,D,L]
  float* vproj = kproj + 65536;              //     262,144: [B,H,L,D]

  // 1) converts
  cvt_bf16<<<(N_TOKENS * EMBED / 4 + 255) / 256, 256, 0, stream>>>(
      (const float4*)query, (u16x4*)qbf, N_TOKENS * EMBED / 4);
  cvt_bf16<<<(EMBED * EMBED / 4 + 255) / 256, 256, 0, stream>>>(
      (const float4*)Wq, (u16x4*)wqb, EMBED * EMBED / 4);
  cvt_bf16<<<(EMBED * EMBED / 4 + 255) / 256, 256, 0, stream>>>(
      (const float4*)Wo, (u16x4*)wob, EMBED * EMBED / 4);

  // 2) K/V projections
  kvproj_kernel<<<512, 256, 0, stream>>>(keyt, valt, Wk, bk, Wv, bv, kproj, vproj);

  // 3) Q = query @ Wq^T + bq  (bf16 out)
  gemm_bt_128<1><<<dim3(EMBED / 128, N_TOKENS / 128), 256, 0, stream>>>(
      qbf, wqb, bq, qout, N_TOKENS, EMBED, EMBED);

  // 4) attention core (ctx bf16), one thread per (token, head), LDS k/v
  attn_kernel<<<N_TOKENS * NHEAD / 256, 256, 0, stream>>>(qout, kproj, vproj, bidx, ctxb);

  // 5) out = ctx @ Wo^T + bo (fp32 out)
  gemm_bt_128<0><<<dim3(EMBED / 128, N_TOKENS / 128), 256, 0, stream>>>(
      ctxb, wob, bo, out, N_TOKENS, EMBED, EMBED);
}